// Round 1
// baseline (24305.524 us; speedup 1.0000x reference)
//
#include <hip/hip_runtime.h>
#include <math.h>

#define NB    256   // batch
#define HDIM  512   // H = K*NP1
#define KDIM  128   // K
#define LDIM  32    // L (scratch slots)
#define ADIM  200   // A
#define NOUTV 8
#define NSTEP 256   // 8 words * 32 inner steps
#define NTHR  512
#define NWG   256
#define WPG   16    // workgroups per group (= batches per group)

__device__ __forceinline__ void group_barrier(unsigned int* ctr, unsigned int target) {
  __syncthreads();
  if (threadIdx.x == 0) {
    __hip_atomic_fetch_add(ctr, 1u, __ATOMIC_RELEASE, __HIP_MEMORY_SCOPE_AGENT);
    while (__hip_atomic_load(ctr, __ATOMIC_ACQUIRE, __HIP_MEMORY_SCOPE_AGENT) < target) {
      __builtin_amdgcn_s_sleep(2);
    }
  }
  __syncthreads();
}

__global__ void __launch_bounds__(NTHR, 1)
sym_kernel(const int* __restrict__ instr,      // (8,256)
           const int* __restrict__ trueact,    // (33,256)
           const float* __restrict__ isv,      // (200,)
           const float* __restrict__ prim_emb, // (16,200)
           const float* __restrict__ gate_w,   // (1,128)
           const float* __restrict__ gate_b,   // (1,)
           const float* __restrict__ w_hh,     // (1536,512)
           const float* __restrict__ b_ih,     // (1536,)
           const float* __restrict__ b_hh,     // (1536,)
           const float* __restrict__ out_w,    // (8,200)
           const float* __restrict__ out_b,    // (8,)
           float* __restrict__ outp,           // 65536 + 8192
           unsigned int* __restrict__ ctrs,
           float* __restrict__ hbuf)           // 2 * 256 * 512 floats
{
  const int tid  = threadIdx.x;
  const int wg   = blockIdx.x;
  const int gidx = wg >> 4;         // group = batch chunk 0..15
  const int jc   = wg & 15;         // j-chunk 0..15 (also: which batch of the group I own for phase A)
  const int myb  = (gidx << 4) | jc;

  __shared__ float sSKt[KDIM][LDIM];     // SK transposed: [k][l], conflict-free reads
  __shared__ float sH[16 * HDIM];        // group's 16 h rows (old h)
  __shared__ float sSV[LDIM * ADIM];     // my batch's scratch, LDS-resident all steps
  __shared__ float sAR[LDIM], sAW[LDIM], sNV[ADIM];
  __shared__ float sGate;

  unsigned int* ctr = ctrs + (gidx << 5);   // one 128B cacheline per group

  // ---- build SK^T (pe[:32] of the sinusoidal table) ----
  for (int i = tid; i < KDIM * LDIM; i += NTHR) {
    const int k = i >> 5, l = i & 31;
    const float div = expf((float)(k & ~1) * (-9.210340371976184f / 128.0f));
    const float ang = (float)l * div;
    sSKt[k][l] = (k & 1) ? cosf(ang) : sinf(ang);
  }
  // ---- h0 (buffer 0) for my batch: pe[0] tiled = 0,1,0,1,... ----
  {
    float* h0 = hbuf + (size_t)myb * HDIM;
    for (int k = tid; k < HDIM; k += NTHR) h0[k] = (k & 1) ? 1.0f : 0.0f;
  }
  // ---- sv0 = broadcast(initial_scratch_value) ----
  for (int i = tid; i < LDIM * ADIM; i += NTHR) sSV[i] = isv[i % ADIM];

  group_barrier(ctr, WPG);   // barrier #1: h0 of all group batches visible

  const float gb = gate_b[0];
  unsigned int bar = 2;

  for (int step = 0; step < NSTEP; ++step, ++bar) {
    const float* hc = hbuf + (size_t)(step & 1) * (NB * HDIM);
    float*       hn = hbuf + (size_t)((step & 1) ^ 1) * (NB * HDIM);

    // ---- stage group's h tile (16 x 512 f32) into LDS, coalesced float4 ----
    {
      const float4* src = (const float4*)(hc + (size_t)(gidx << 4) * HDIM);
      float4* dst = (float4*)sH;
      #pragma unroll
      for (int i = 0; i < (16 * HDIM / 4) / NTHR; ++i)
        dst[tid + i * NTHR] = src[tid + i * NTHR];
    }
    __syncthreads();

    const float* hm = sH + jc * HDIM;   // my batch's old h

    // ---- phase A1: read/write attention softmax (lanes 0..63), gate (lanes 64..127) ----
    if (tid < 64) {
      const int l = tid & 31, sel = tid >> 5;
      const float* p = hm + KDIM + sel * KDIM;     // read_p @128, write_p @256
      float acc = 0.f;
      #pragma unroll 4
      for (int k = 0; k < KDIM; ++k) acc = fmaf(p[k], sSKt[k][l], acc);
      float mx = acc;
      #pragma unroll
      for (int m = 1; m < 32; m <<= 1) mx = fmaxf(mx, __shfl_xor(mx, m, 32));
      const float e = __expf(acc - mx);
      float s = e;
      #pragma unroll
      for (int m = 1; m < 32; m <<= 1) s += __shfl_xor(s, m, 32);
      (sel ? sAW : sAR)[l] = e / s;
    } else if (tid < 128) {
      const int k = tid - 64;
      float part = fmaf(hm[384 + k], gate_w[k], hm[448 + k] * gate_w[64 + k]);
      #pragma unroll
      for (int m = 1; m < 64; m <<= 1) part += __shfl_xor(part, m, 64);
      if (k == 0) sGate = 1.0f / (1.0f + __expf(-(part + gb)));
    }
    __syncthreads();

    // ---- phase A2: read_val -> new_val ----
    {
      const int word = instr[(step >> 5) * NB + myb];
      const float* prim = prim_emb + word * ADIM;
      if (tid < ADIM) {
        float rv = 0.f;
        #pragma unroll 8
        for (int l = 0; l < LDIM; ++l) rv = fmaf(sAR[l], sSV[l * ADIM + tid], rv);
        const float g = sGate;
        sNV[tid] = fmaf(g, prim[tid], (1.0f - g) * rv);
      }
    }
    __syncthreads();

    // ---- phase A3: scratch update sv = wm*nv + (1-wm)*sv ----
    for (int i = tid; i < LDIM * ADIM; i += NTHR) {
      const int l = i / ADIM;
      const int a = i - l * ADIM;
      const float w = sAW[l];
      sSV[i] = fmaf(w, sNV[a], (1.0f - w) * sSV[i]);
    }

    // ---- phase B: gh tile (16 batches x 32 j x 3 gates) + GRU update ----
    {
      const int br = tid >> 5;            // batch row in group 0..15
      const int c  = tid & 31;
      const int j  = (jc << 5) | c;       // 0..511
      const float4* h4 = (const float4*)(sH + br * HDIM);
      const float4* wr = (const float4*)(w_hh + (size_t)j * HDIM);
      const float4* wz = (const float4*)(w_hh + (size_t)(HDIM + j) * HDIM);
      const float4* wn = (const float4*)(w_hh + (size_t)(2 * HDIM + j) * HDIM);
      float aR = 0.f, aZ = 0.f, aN = 0.f;
      #pragma unroll 4
      for (int k4 = 0; k4 < HDIM / 4; ++k4) {
        const float4 h = h4[k4];
        const float4 a = wr[k4], b = wz[k4], cc = wn[k4];
        aR = fmaf(h.x, a.x,  fmaf(h.y, a.y,  fmaf(h.z, a.z,  fmaf(h.w, a.w,  aR))));
        aZ = fmaf(h.x, b.x,  fmaf(h.y, b.y,  fmaf(h.z, b.z,  fmaf(h.w, b.w,  aZ))));
        aN = fmaf(h.x, cc.x, fmaf(h.y, cc.y, fmaf(h.z, cc.z, fmaf(h.w, cc.w, aN))));
      }
      const float r = 1.0f / (1.0f + __expf(-(aR + b_hh[j] + b_ih[j])));
      const float z = 1.0f / (1.0f + __expf(-(aZ + b_hh[HDIM + j] + b_ih[HDIM + j])));
      const float n = tanhf(fmaf(r, aN + b_hh[2 * HDIM + j], b_ih[2 * HDIM + j]));
      const float hold = sH[br * HDIM + j];
      hn[(size_t)((gidx << 4) + br) * HDIM + j] = fmaf(z, hold - n, n);  // (1-z)n + z*h
    }

    group_barrier(ctr, bar * WPG);
  }

  // ---- epilogue: actions = log_softmax(sv @ out_w.T + out_b), transposed (b, v, l) ----
  if (tid < 256) {
    const int l = tid >> 3, v = tid & 7;
    const float* svrow = sSV + l * ADIM;
    const float* wrow  = out_w + v * ADIM;
    float acc = out_b[v];
    #pragma unroll 8
    for (int a = 0; a < ADIM; ++a) acc = fmaf(svrow[a], wrow[a], acc);
    float mx = acc;
    #pragma unroll
    for (int m = 1; m < 8; m <<= 1) mx = fmaxf(mx, __shfl_xor(mx, m, 8));
    const float e = __expf(acc - mx);
    float s = e;
    #pragma unroll
    for (int m = 1; m < 8; m <<= 1) s += __shfl_xor(s, m, 8);
    outp[(size_t)myb * (NOUTV * LDIM) + v * LDIM + l] = acc - mx - logf(s);
  }
  // ---- output 1: padded_true.T as float ----
  if (tid < LDIM) {
    outp[NB * NOUTV * LDIM + myb * LDIM + tid] = (float)trueact[(tid + 1) * NB + myb];
  }
}

extern "C" void kernel_launch(void* const* d_in, const int* in_sizes, int n_in,
                              void* d_out, int out_size, void* d_ws, size_t ws_size,
                              hipStream_t stream) {
  const int*   instr   = (const int*)d_in[0];
  const int*   trueact = (const int*)d_in[1];
  const float* isv     = (const float*)d_in[2];
  // d_in[3] = program_emb (unused by reference math)
  const float* prim    = (const float*)d_in[4];
  const float* gate_w  = (const float*)d_in[5];
  const float* gate_b  = (const float*)d_in[6];
  // d_in[7] = w_ih (multiplied by zeros; only b_ih matters)
  const float* w_hh    = (const float*)d_in[8];
  const float* b_ih    = (const float*)d_in[9];
  const float* b_hh    = (const float*)d_in[10];
  const float* out_w   = (const float*)d_in[11];
  const float* out_b   = (const float*)d_in[12];
  float* outp = (float*)d_out;

  unsigned int* ctrs = (unsigned int*)d_ws;                 // 16 groups * 128B
  float* hbuf = (float*)((char*)d_ws + 4096);               // 2 * 256 * 512 f32 = 1 MB

  hipMemsetAsync(d_ws, 0, 4096, stream);                    // reset barrier counters each call

  void* args[] = { (void*)&instr, (void*)&trueact, (void*)&isv, (void*)&prim,
                   (void*)&gate_w, (void*)&gate_b, (void*)&w_hh, (void*)&b_ih,
                   (void*)&b_hh, (void*)&out_w, (void*)&out_b, (void*)&outp,
                   (void*)&ctrs, (void*)&hbuf };
  hipLaunchCooperativeKernel((const void*)sym_kernel, dim3(NWG), dim3(NTHR),
                             args, 0, stream);
}

// Round 2
// 4507.575 us; speedup vs baseline: 5.3922x; 5.3922x over previous
//
#include <hip/hip_runtime.h>
#include <math.h>

#define NB    256   // batch
#define HDIM  512   // H = K*NP1
#define KDIM  128   // K
#define LDIM  32    // L (scratch slots)
#define ADIM  200   // A
#define NOUTV 8
#define NSTEP 256   // 8 words * 32 inner steps
#define NTHR  512
#define NWG   256
#define WPG   16    // workgroups per group (= batches per group)

__device__ __forceinline__ void group_barrier(unsigned int* ctr, unsigned int target) {
  __syncthreads();
  if (threadIdx.x == 0) {
    __hip_atomic_fetch_add(ctr, 1u, __ATOMIC_RELEASE, __HIP_MEMORY_SCOPE_AGENT);
    while (__hip_atomic_load(ctr, __ATOMIC_ACQUIRE, __HIP_MEMORY_SCOPE_AGENT) < target) {
      __builtin_amdgcn_s_sleep(1);
    }
  }
  __syncthreads();
}

// padded h layout in LDS: float4 slot (b,ks,i) = (b*16+ks)*9 + i, i=0..7
// element h[b][k]: ks=k>>5, i=(k>>2)&7, e=k&3
#define HLOAD(b,k) sHf[((((b)*16 + ((k)>>5))*9 + (((k)>>2)&7))<<2) + ((k)&3)]

__global__ void __launch_bounds__(NTHR, 1)
sym_kernel(const int* __restrict__ instr,      // (8,256)
           const int* __restrict__ trueact,    // (33,256)
           const float* __restrict__ isv,      // (200,)
           const float* __restrict__ prim_emb, // (16,200)
           const float* __restrict__ gate_w,   // (1,128)
           const float* __restrict__ gate_b,   // (1,)
           const float* __restrict__ w_hh,     // (1536,512)
           const float* __restrict__ b_ih,     // (1536,)
           const float* __restrict__ b_hh,     // (1536,)
           const float* __restrict__ out_w,    // (8,200)
           const float* __restrict__ out_b,    // (8,)
           float* __restrict__ outp,           // 65536 + 8192
           unsigned int* __restrict__ ctrs,
           float* __restrict__ hbuf)           // 2 * 256 * 512 floats
{
  const int tid  = threadIdx.x;
  const int wgid = blockIdx.x;
  // XCD-local groups: members of a group share bid%8 (one XCD under round-robin)
  const int x    = wgid & 7, q = wgid >> 3;
  const int gidx = x | ((q & 1) << 3);   // group 0..15
  const int jc   = q >> 1;               // member 0..15 (j-chunk; also my phase-A batch)
  const int myb  = (gidx << 4) | jc;

  __shared__ float  sSKt[KDIM][LDIM];    // SK^T [k][l]
  __shared__ float4 sH4[16 * 16 * 9];    // padded h tile (16 batches)
  __shared__ float  sSV[LDIM * ADIM];    // my batch's scratch
  __shared__ float  sGW[KDIM];
  __shared__ float  sAR[LDIM], sAW[LDIM], sNV[ADIM];
  __shared__ float  sGate;
  const float* sHf = (const float*)sH4;

  unsigned int* ctr = ctrs + (gidx << 5);

  // ---- lane mapping for GEMM ----
  const int lane = tid & 63;
  const int wv   = tid >> 6;            // wave 0..7
  const int ks   = lane & 15;           // k-slice (32 k each)
  const int cc   = lane >> 4;           // 0..3
  const int c    = (wv << 2) | cc;      // j-col within chunk 0..31
  const int jj   = (jc << 5) | c;       // j 0..511

  // ---- persistent weights: 96 f32 in VGPRs for all 256 steps ----
  float4 wreg[3][8];
  float  bihv[3], bhhv[3];
  #pragma unroll
  for (int g = 0; g < 3; ++g) {
    const float* wrow = w_hh + (size_t)(g * HDIM + jj) * HDIM + ks * 32;
    #pragma unroll
    for (int q8 = 0; q8 < 8; ++q8) wreg[g][q8] = ((const float4*)wrow)[q8];
    bihv[g] = b_ih[g * HDIM + jj];
    bhhv[g] = b_hh[g * HDIM + jj];
  }

  // ---- build SK^T ----
  for (int i = tid; i < KDIM * LDIM; i += NTHR) {
    const int k = i >> 5, l = i & 31;
    const float div = expf((float)(k & ~1) * (-9.210340371976184f / 128.0f));
    const float ang = (float)l * div;
    sSKt[k][l] = (k & 1) ? cosf(ang) : sinf(ang);
  }
  if (tid < KDIM) sGW[tid] = gate_w[tid];
  // ---- h0 (buffer 0) for my batch: pe[0] tiled = 0,1,0,1,... ----
  {
    float* h0 = hbuf + (size_t)myb * HDIM;
    for (int k = tid; k < HDIM; k += NTHR) h0[k] = (k & 1) ? 1.0f : 0.0f;
  }
  // ---- sv0 ----
  for (int i = tid; i < LDIM * ADIM; i += NTHR) sSV[i] = isv[i % ADIM];

  group_barrier(ctr, WPG);

  const float gb = gate_b[0];
  unsigned int bar = 2;

  for (int step = 0; step < NSTEP; ++step, ++bar) {
    const float* hc = hbuf + (size_t)(step & 1) * (NB * HDIM);
    float*       hn = hbuf + (size_t)((step & 1) ^ 1) * (NB * HDIM);

    // ---- stage group's h tile into padded LDS ----
    {
      const float4* src = (const float4*)(hc + (size_t)(gidx << 4) * HDIM);
      #pragma unroll
      for (int it = 0; it < 4; ++it) {
        const int idx = tid + it * NTHR;       // 0..2047
        const int b = idx >> 7, sl = idx & 127;
        sH4[(b * 16 + (sl >> 3)) * 9 + (sl & 7)] = src[idx];
      }
    }
    __syncthreads();

    // ---- phase B: GEMM with register-resident weights ----
    #pragma unroll 1
    for (int b = 0; b < 16; ++b) {
      const int sb = (b * 16 + ks) * 9;
      float4 h4[8];
      #pragma unroll
      for (int q8 = 0; q8 < 8; ++q8) h4[q8] = sH4[sb + q8];
      float aR = 0.f, aZ = 0.f, aN = 0.f;
      #pragma unroll
      for (int q8 = 0; q8 < 8; ++q8) {
        const float4 h = h4[q8];
        const float4 wa = wreg[0][q8], wb = wreg[1][q8], wc = wreg[2][q8];
        aR = fmaf(h.x, wa.x, fmaf(h.y, wa.y, fmaf(h.z, wa.z, fmaf(h.w, wa.w, aR))));
        aZ = fmaf(h.x, wb.x, fmaf(h.y, wb.y, fmaf(h.z, wb.z, fmaf(h.w, wb.w, aZ))));
        aN = fmaf(h.x, wc.x, fmaf(h.y, wc.y, fmaf(h.z, wc.z, fmaf(h.w, wc.w, aN))));
      }
      #pragma unroll
      for (int m = 1; m <= 8; m <<= 1) {   // reduce over ks (lane bits 0..3)
        aR += __shfl_xor(aR, m);
        aZ += __shfl_xor(aZ, m);
        aN += __shfl_xor(aN, m);
      }
      const float r = 1.0f / (1.0f + __expf(-(aR + bhhv[0] + bihv[0])));
      const float z = 1.0f / (1.0f + __expf(-(aZ + bhhv[1] + bihv[1])));
      const float n = tanhf(fmaf(r, aN + bhhv[2], bihv[2]));
      if (ks == 0) {
        const float hold = HLOAD(b, jj);
        hn[(size_t)((gidx << 4) + b) * HDIM + jj] = fmaf(z, hold - n, n);
      }
    }

    // ---- phase A1: attention softmax (wave 0), gate (wave 1) ----
    if (tid < 64) {
      const int l = tid & 31, sel = tid >> 5;
      const int pb = KDIM + sel * KDIM;
      float acc = 0.f;
      #pragma unroll 4
      for (int k = 0; k < KDIM; ++k) acc = fmaf(HLOAD(jc, pb + k), sSKt[k][l], acc);
      float mx = acc;
      #pragma unroll
      for (int m = 1; m < 32; m <<= 1) mx = fmaxf(mx, __shfl_xor(mx, m, 32));
      const float e = __expf(acc - mx);
      float s = e;
      #pragma unroll
      for (int m = 1; m < 32; m <<= 1) s += __shfl_xor(s, m, 32);
      (sel ? sAW : sAR)[l] = e / s;
    } else if (tid < 128) {
      const int k = tid - 64;
      float part = fmaf(HLOAD(jc, 384 + k), sGW[k], HLOAD(jc, 448 + k) * sGW[64 + k]);
      #pragma unroll
      for (int m = 1; m < 64; m <<= 1) part += __shfl_xor(part, m, 64);
      if (k == 0) sGate = 1.0f / (1.0f + __expf(-(part + gb)));
    }
    __syncthreads();

    // ---- phase A2: read_val -> new_val ----
    {
      const int word = instr[(step >> 5) * NB + myb];
      const float* prim = prim_emb + word * ADIM;
      if (tid < ADIM) {
        float rv = 0.f;
        #pragma unroll 8
        for (int l = 0; l < LDIM; ++l) rv = fmaf(sAR[l], sSV[l * ADIM + tid], rv);
        const float g = sGate;
        sNV[tid] = fmaf(g, prim[tid], (1.0f - g) * rv);
      }
    }
    __syncthreads();

    // ---- phase A3: scratch update ----
    for (int i = tid; i < LDIM * ADIM; i += NTHR) {
      const int l = i / ADIM;
      const int a = i - l * ADIM;
      const float w = sAW[l];
      sSV[i] = fmaf(w, sNV[a], (1.0f - w) * sSV[i]);
    }

    group_barrier(ctr, bar * WPG);
  }

  // ---- epilogue: actions = log_softmax(sv @ out_w.T + out_b), (b, v, l) ----
  if (tid < 256) {
    const int l = tid >> 3, v = tid & 7;
    const float* svrow = sSV + l * ADIM;
    const float* wrow  = out_w + v * ADIM;
    float acc = out_b[v];
    #pragma unroll 8
    for (int a = 0; a < ADIM; ++a) acc = fmaf(svrow[a], wrow[a], acc);
    float mx = acc;
    #pragma unroll
    for (int m = 1; m < 8; m <<= 1) mx = fmaxf(mx, __shfl_xor(mx, m, 8));
    const float e = __expf(acc - mx);
    float s = e;
    #pragma unroll
    for (int m = 1; m < 8; m <<= 1) s += __shfl_xor(s, m, 8);
    outp[(size_t)myb * (NOUTV * LDIM) + v * LDIM + l] = acc - mx - logf(s);
  }
  if (tid < LDIM) {
    outp[NB * NOUTV * LDIM + myb * LDIM + tid] = (float)trueact[(tid + 1) * NB + myb];
  }
}

extern "C" void kernel_launch(void* const* d_in, const int* in_sizes, int n_in,
                              void* d_out, int out_size, void* d_ws, size_t ws_size,
                              hipStream_t stream) {
  const int*   instr   = (const int*)d_in[0];
  const int*   trueact = (const int*)d_in[1];
  const float* isv     = (const float*)d_in[2];
  // d_in[3] = program_emb (unused by reference math)
  const float* prim    = (const float*)d_in[4];
  const float* gate_w  = (const float*)d_in[5];
  const float* gate_b  = (const float*)d_in[6];
  // d_in[7] = w_ih (multiplied by zeros; only b_ih matters)
  const float* w_hh    = (const float*)d_in[8];
  const float* b_ih    = (const float*)d_in[9];
  const float* b_hh    = (const float*)d_in[10];
  const float* out_w   = (const float*)d_in[11];
  const float* out_b   = (const float*)d_in[12];
  float* outp = (float*)d_out;

  unsigned int* ctrs = (unsigned int*)d_ws;          // 16 groups * 128B
  float* hbuf = (float*)((char*)d_ws + 4096);        // 2 * 256 * 512 f32 = 1 MB

  hipMemsetAsync(d_ws, 0, 4096, stream);

  void* args[] = { (void*)&instr, (void*)&trueact, (void*)&isv, (void*)&prim,
                   (void*)&gate_w, (void*)&gate_b, (void*)&w_hh, (void*)&b_ih,
                   (void*)&b_hh, (void*)&out_w, (void*)&out_b, (void*)&outp,
                   (void*)&ctrs, (void*)&hbuf };
  hipLaunchCooperativeKernel((const void*)sym_kernel, dim3(NWG), dim3(NTHR),
                             args, 0, stream);
}

// Round 3
// 2075.995 us; speedup vs baseline: 11.7079x; 2.1713x over previous
//
#include <hip/hip_runtime.h>
#include <math.h>

#define NB    256
#define HDIM  512
#define LDIM  32
#define ADIM  200
#define NOUTV 8
#define NSTEP 256
#define NTHR  512
#define NWG   256
#define WPG   16
#define SCST  21    // sC row stride (odd -> conflict-free combine reads)

typedef __attribute__((ext_vector_type(8))) short sh8;
typedef __attribute__((ext_vector_type(4))) float f4;

union FU { uint4 u; sh8 s; };

__device__ __forceinline__ float b2f(unsigned int low16) { return __uint_as_float(low16 << 16); }

__device__ __forceinline__ void group_barrier(unsigned int* ctr, unsigned int target) {
  __syncthreads();
  if (threadIdx.x == 0) {
    __hip_atomic_fetch_add(ctr, 1u, __ATOMIC_RELEASE, __HIP_MEMORY_SCOPE_AGENT);
    while (__hip_atomic_load(ctr, __ATOMIC_ACQUIRE, __HIP_MEMORY_SCOPE_AGENT) < target) {
      __builtin_amdgcn_s_sleep(1);
    }
  }
  __syncthreads();
}

__global__ void __launch_bounds__(NTHR, 1)
sym_kernel(const int* __restrict__ instr,      // (8,256)
           const int* __restrict__ trueact,    // (33,256)
           const float* __restrict__ isv,      // (200,)
           const float* __restrict__ prim_emb, // (16,200)
           const float* __restrict__ gate_w,   // (1,128)
           const float* __restrict__ gate_b,   // (1,)
           const float* __restrict__ w_hh,     // (1536,512)
           const float* __restrict__ b_ih,     // (1536,)
           const float* __restrict__ b_hh,     // (1536,)
           const float* __restrict__ out_w,    // (8,200)
           const float* __restrict__ out_b,    // (8,)
           float* __restrict__ outp,           // 65536 + 8192
           unsigned int* __restrict__ ctrs,
           unsigned int* __restrict__ hbuf)    // 2 * 256 * 512 packed u32 (hi16|lo16)
{
  const int tid  = threadIdx.x;
  const int wgid = blockIdx.x;
  // XCD-local groups: members of a group share wgid%8 (one XCD under round-robin)
  const int x    = wgid & 7, q = wgid >> 3;
  const int gidx = x | ((q & 1) << 3);   // group 0..15
  const int jc   = q >> 1;               // member 0..15 (j-chunk; also my phase-A batch)
  const int myb  = (gidx << 4) | jc;
  const int lane = tid & 63, wv = tid >> 6;

  __shared__ __align__(16) unsigned short sHi[16 * 512];   // h hi-plane, XOR-swizzled
  __shared__ __align__(16) unsigned short sLo[16 * 512];   // h lo-plane
  __shared__ float sC[96 * SCST];                          // GEMM output r/z/n pre-acts
  __shared__ __align__(16) float sSV[LDIM * ADIM];         // my batch's scratch
  __shared__ __align__(16) float sNV[ADIM];
  __shared__ float sSKt[128 * 32];                         // SK^T [k][l] (prologue only)
  __shared__ __align__(16) float sPE[16 * ADIM];           // primitive_emb cache
  __shared__ float sAR[LDIM], sAW[LDIM];
  __shared__ float sGate;

  unsigned int* ctr = ctrs + (gidx << 5);

  // ---- per-thread loop invariants ----
  unsigned int wordpack = 0;
  #pragma unroll
  for (int wi = 0; wi < 8; ++wi)
    wordpack |= ((unsigned)instr[wi * NB + myb] & 15u) << (4 * wi);

  const int jj_t = (jc << 5) | (tid & 31);   // my combine j
  const float bi0 = b_ih[jj_t], bi1 = b_ih[512 + jj_t], bi2 = b_ih[1024 + jj_t];
  const float bh0 = b_hh[jj_t], bh1 = b_hh[512 + jj_t], bh2 = b_hh[1024 + jj_t];

  // ---- prologue fills ----
  for (int i = tid; i < 128 * 32; i += NTHR) {
    const int k = i >> 5, l = i & 31;
    const float div = expf((float)(k & ~1) * (-9.210340371976184f / 128.0f));
    const float ang = (float)l * div;
    sSKt[i] = (k & 1) ? cosf(ang) : sinf(ang);
  }
  for (int i = tid; i < 16 * ADIM; i += NTHR) sPE[i] = prim_emb[i];
  for (int i = tid; i < LDIM * ADIM; i += NTHR) sSV[i] = isv[i % ADIM];
  {
    unsigned int* h0 = hbuf + (size_t)myb * HDIM;
    for (int k = tid; k < HDIM; k += NTHR) h0[k] = (k & 1) ? 0x3F800000u : 0u;  // bf16(1.0)|0
  }
  __syncthreads();   // sSKt ready

  // ---- shared register file: weights (wv<6) / SK column (wv6) / gate_w (wv7) ----
  unsigned int reg[128];
  if (wv < 6) {
    const int n = lane & 15, quad = lane >> 4;
    const int row96 = (wv << 4) | n;
    const int g = row96 >> 5;
    const int jj = (jc << 5) | (row96 & 31);
    const float* wrow = w_hh + (size_t)(g * 512 + jj) * 512;
    #pragma unroll
    for (int kk = 0; kk < 16; ++kk) {
      const float4 w0 = *(const float4*)(wrow + kk * 32 + quad * 8);
      const float4 w1 = *(const float4*)(wrow + kk * 32 + quad * 8 + 4);
      float e[8] = {w0.x, w0.y, w0.z, w0.w, w1.x, w1.y, w1.z, w1.w};
      unsigned int hi16[8], lo16[8];
      #pragma unroll
      for (int t = 0; t < 8; ++t) {
        const unsigned int b = __float_as_uint(e[t]);
        hi16[t] = b >> 16;
        const float rest = e[t] - __uint_as_float(b & 0xFFFF0000u);
        lo16[t] = __float_as_uint(rest) >> 16;
      }
      #pragma unroll
      for (int p = 0; p < 4; ++p) {
        reg[kk * 4 + p]      = hi16[2 * p] | (hi16[2 * p + 1] << 16);
        reg[64 + kk * 4 + p] = lo16[2 * p] | (lo16[2 * p + 1] << 16);
      }
    }
  } else if (wv == 6) {
    const int l = lane & 31;
    #pragma unroll
    for (int k = 0; k < 128; ++k) reg[k] = __float_as_uint(sSKt[k * 32 + l]);
  } else {
    reg[0] = __float_as_uint(gate_w[2 * lane]);
    reg[1] = __float_as_uint(gate_w[2 * lane + 1]);
  }

  group_barrier(ctr, WPG);   // h0 of all group batches visible

  const float gbias = gate_b[0];
  unsigned int bar = 2;

  for (int step = 0; step < NSTEP; ++step, ++bar) {
    const unsigned int* hc = hbuf + (size_t)(step & 1) * (NB * HDIM);
    unsigned int*       hn = hbuf + (size_t)((step & 1) ^ 1) * (NB * HDIM);

    // ---- stage packed h -> swizzled hi/lo planes (1024 chunks of 8 elems) ----
    {
      const uint4* src = (const uint4*)(hc + (size_t)(gidx << 4) * HDIM);
      #pragma unroll
      for (int it = 0; it < 2; ++it) {
        const int c   = tid + it * NTHR;          // 0..1023
        const int row = c >> 6;
        const int kb  = (c & 63) << 4;            // byte offset within row (bf16 units)
        const uint4 x0 = src[c * 2], x1 = src[c * 2 + 1];
        const int off = row * 1024 + (kb ^ ((row & 7) << 4));
        *(uint4*)((char*)sHi + off) = make_uint4(
          (x0.x >> 16) | (x0.y & 0xFFFF0000u),
          (x0.z >> 16) | (x0.w & 0xFFFF0000u),
          (x1.x >> 16) | (x1.y & 0xFFFF0000u),
          (x1.z >> 16) | (x1.w & 0xFFFF0000u));
        *(uint4*)((char*)sLo + off) = make_uint4(
          (x0.x & 0xFFFFu) | (x0.y << 16),
          (x0.z & 0xFFFFu) | (x0.w << 16),
          (x1.x & 0xFFFFu) | (x1.y << 16),
          (x1.z & 0xFFFFu) | (x1.w << 16));
      }
    }
    __syncthreads();

    // ---- region 1: MFMA (waves 0-5) || attention (wave 6) || gate (wave 7) ----
    if (wv < 6) {
      const int n = lane & 15, quad = lane >> 4;
      const int sw = (n & 7) << 4;
      f4 a0 = {0.f, 0.f, 0.f, 0.f}, a1 = a0, a2 = a0;
      #pragma unroll
      for (int kk = 0; kk < 16; ++kk) {
        const int off = n * 1024 + (((kk << 6) | (quad << 4)) ^ sw);
        FU fah, fal, fbh, fbl;
        fah.u = *(const uint4*)((const char*)sHi + off);
        fal.u = *(const uint4*)((const char*)sLo + off);
        fbh.u = make_uint4(reg[kk * 4], reg[kk * 4 + 1], reg[kk * 4 + 2], reg[kk * 4 + 3]);
        fbl.u = make_uint4(reg[64 + kk * 4], reg[64 + kk * 4 + 1], reg[64 + kk * 4 + 2], reg[64 + kk * 4 + 3]);
        a0 = __builtin_amdgcn_mfma_f32_16x16x32_bf16(fah.s, fbh.s, a0, 0, 0, 0);
        a1 = __builtin_amdgcn_mfma_f32_16x16x32_bf16(fah.s, fbl.s, a1, 0, 0, 0);
        a2 = __builtin_amdgcn_mfma_f32_16x16x32_bf16(fal.s, fbh.s, a2, 0, 0, 0);
      }
      const int row96 = (wv << 4) | n;
      #pragma unroll
      for (int i = 0; i < 4; ++i)
        sC[row96 * SCST + (quad << 2) + i] = a0[i] + a1[i] + a2[i];
    } else if (wv == 6) {
      const int l = lane & 31, sel = lane >> 5;
      const int sw = (jc & 7) << 4;
      float acc = 0.f;
      #pragma unroll
      for (int c = 0; c < 32; ++c) {
        const int kbyte = (128 + sel * 128 + c * 4) * 2;
        const int off = jc * 1024 + (kbyte ^ sw);
        const uint2 hb = *(const uint2*)((const char*)sHi + off);
        const uint2 lb = *(const uint2*)((const char*)sLo + off);
        const float e0 = b2f(hb.x & 0xFFFFu) + b2f(lb.x & 0xFFFFu);
        const float e1 = __uint_as_float(hb.x & 0xFFFF0000u) + __uint_as_float(lb.x & 0xFFFF0000u);
        const float e2 = b2f(hb.y & 0xFFFFu) + b2f(lb.y & 0xFFFFu);
        const float e3 = __uint_as_float(hb.y & 0xFFFF0000u) + __uint_as_float(lb.y & 0xFFFF0000u);
        acc = fmaf(e0, __uint_as_float(reg[c * 4]), acc);
        acc = fmaf(e1, __uint_as_float(reg[c * 4 + 1]), acc);
        acc = fmaf(e2, __uint_as_float(reg[c * 4 + 2]), acc);
        acc = fmaf(e3, __uint_as_float(reg[c * 4 + 3]), acc);
      }
      float mx = acc;
      #pragma unroll
      for (int m = 1; m < 32; m <<= 1) mx = fmaxf(mx, __shfl_xor(mx, m, 32));
      const float ev = __expf(acc - mx);
      float s = ev;
      #pragma unroll
      for (int m = 1; m < 32; m <<= 1) s += __shfl_xor(s, m, 32);
      (sel ? sAW : sAR)[l] = ev / s;
    } else {
      const int sw = (jc & 7) << 4;
      const int off = jc * 1024 + ((768 + 4 * lane) ^ sw);
      const unsigned int hb = *(const unsigned int*)((const char*)sHi + off);
      const unsigned int lb = *(const unsigned int*)((const char*)sLo + off);
      const float e0 = b2f(hb & 0xFFFFu) + b2f(lb & 0xFFFFu);
      const float e1 = __uint_as_float(hb & 0xFFFF0000u) + __uint_as_float(lb & 0xFFFF0000u);
      float part = fmaf(e0, __uint_as_float(reg[0]), e1 * __uint_as_float(reg[1]));
      #pragma unroll
      for (int m = 1; m < 64; m <<= 1) part += __shfl_xor(part, m, 64);
      if (lane == 0) sGate = 1.0f / (1.0f + __expf(-(part + gbias)));
    }
    __syncthreads();

    // ---- region 2: GRU combine (all) + A2 read_val (tid<200) ----
    {
      const int b = tid >> 5, jcol = tid & 31;
      const float accR = sC[jcol * SCST + b];
      const float accZ = sC[(32 + jcol) * SCST + b];
      const float accN = sC[(64 + jcol) * SCST + b];
      const float r  = 1.f / (1.f + __expf(-(accR + bh0 + bi0)));
      const float z  = 1.f / (1.f + __expf(-(accZ + bh1 + bi1)));
      const float nn = tanhf(fmaf(r, accN + bh2, bi2));
      const int hoff = b * 1024 + ((jj_t * 2) ^ ((b & 7) << 4));
      const float hold = b2f(*(const unsigned short*)((const char*)sHi + hoff))
                       + b2f(*(const unsigned short*)((const char*)sLo + hoff));
      const float hnew = fmaf(z, hold - nn, nn);
      const unsigned int hibits = __float_as_uint(hnew) & 0xFFFF0000u;
      const float rest = hnew - __uint_as_float(hibits);
      const unsigned int lobits = __float_as_uint(rest) >> 16;
      hn[(size_t)((gidx << 4) + b) * HDIM + jj_t] = hibits | lobits;
    }
    if (tid < ADIM) {
      const int word = (wordpack >> ((step >> 5) << 2)) & 15u;
      float rv = 0.f;
      #pragma unroll 8
      for (int l = 0; l < LDIM; ++l) rv = fmaf(sAR[l], sSV[l * ADIM + tid], rv);
      const float g = sGate;
      sNV[tid] = fmaf(g, sPE[word * ADIM + tid], (1.f - g) * rv);
    }
    __syncthreads();

    // ---- region 3: scratch update (vectorized) ----
    {
      const f4* nv4 = (const f4*)sNV;
      f4* sv4 = (f4*)sSV;
      #pragma unroll
      for (int it = 0; it < 4; ++it) {
        const int s4 = tid + it * NTHR;
        if (s4 < 1600) {
          const int l = s4 / 50, a4 = s4 - l * 50;
          const float w = sAW[l];
          const f4 nv = nv4[a4];
          f4 sv = sv4[s4];
          sv.x = fmaf(w, nv.x - sv.x, sv.x);
          sv.y = fmaf(w, nv.y - sv.y, sv.y);
          sv.z = fmaf(w, nv.z - sv.z, sv.z);
          sv.w = fmaf(w, nv.w - sv.w, sv.w);
          sv4[s4] = sv;
        }
      }
    }

    group_barrier(ctr, bar * WPG);
  }

  // ---- epilogue: actions = log_softmax(sv @ out_w.T + out_b), (b, v, l) ----
  if (tid < 256) {
    const int l = tid >> 3, v = tid & 7;
    const float* svrow = sSV + l * ADIM;
    const float* wrow  = out_w + v * ADIM;
    float acc = out_b[v];
    #pragma unroll 8
    for (int a = 0; a < ADIM; ++a) acc = fmaf(svrow[a], wrow[a], acc);
    float mx = acc;
    #pragma unroll
    for (int m = 1; m < 8; m <<= 1) mx = fmaxf(mx, __shfl_xor(mx, m, 8));
    const float e = __expf(acc - mx);
    float s = e;
    #pragma unroll
    for (int m = 1; m < 8; m <<= 1) s += __shfl_xor(s, m, 8);
    outp[(size_t)myb * (NOUTV * LDIM) + v * LDIM + l] = acc - mx - logf(s);
  }
  if (tid < LDIM) {
    outp[NB * NOUTV * LDIM + myb * LDIM + tid] = (float)trueact[(tid + 1) * NB + myb];
  }
}

extern "C" void kernel_launch(void* const* d_in, const int* in_sizes, int n_in,
                              void* d_out, int out_size, void* d_ws, size_t ws_size,
                              hipStream_t stream) {
  const int*   instr   = (const int*)d_in[0];
  const int*   trueact = (const int*)d_in[1];
  const float* isv     = (const float*)d_in[2];
  // d_in[3] = program_emb (unused by reference math)
  const float* prim    = (const float*)d_in[4];
  const float* gate_w  = (const float*)d_in[5];
  const float* gate_b  = (const float*)d_in[6];
  // d_in[7] = w_ih (multiplied by zeros; only b_ih matters)
  const float* w_hh    = (const float*)d_in[8];
  const float* b_ih    = (const float*)d_in[9];
  const float* b_hh    = (const float*)d_in[10];
  const float* out_w   = (const float*)d_in[11];
  const float* out_b   = (const float*)d_in[12];
  float* outp = (float*)d_out;

  unsigned int* ctrs = (unsigned int*)d_ws;              // 16 groups * 128B
  unsigned int* hbuf = (unsigned int*)((char*)d_ws + 4096);  // 2 * 256 * 512 u32 = 1 MB

  hipMemsetAsync(d_ws, 0, 4096, stream);

  void* args[] = { (void*)&instr, (void*)&trueact, (void*)&isv, (void*)&prim,
                   (void*)&gate_w, (void*)&gate_b, (void*)&w_hh, (void*)&b_ih,
                   (void*)&b_hh, (void*)&out_w, (void*)&out_b, (void*)&outp,
                   (void*)&ctrs, (void*)&hbuf };
  hipLaunchCooperativeKernel((const void*)sym_kernel, dim3(NWG), dim3(NTHR),
                             args, 0, stream);
}